// Round 5
// baseline (253.522 us; speedup 1.0000x reference)
//
#include <hip/hip_runtime.h>

// Newton-Schulz batched inverse, 1024 x (128x128) fp32.
// R5: 1024 threads / 16 waves, ONE mm1-tile + ONE mm2-tile per wave per iter
// (peak live regs ~75 unified -> no spill at the 128-reg/wave budget).
// fp32 W stage stays resident in LDS (129KB total, 1 block/CU); xrm built by
// LDS transpose (no global re-read). hi-only bf16 X (2d0-d1-d2 cancellation).

#define NN 128

typedef __attribute__((ext_vector_type(8))) short bf16x8;
typedef __attribute__((ext_vector_type(16))) float f32x16;
typedef __attribute__((ext_vector_type(4))) float f32x4;
typedef __attribute__((ext_vector_type(4))) unsigned short us4;

// LDS layout (bytes) — no aliasing except scr==xcm (band-self-owned):
#define STAGE_OFF 0        // fp32 W [128][128], live whole kernel   65536
#define XRM_OFF   65536    // X row-major hi bf16, swizzled          32768
#define XCM_OFF   98304    // X col-major hi bf16, swizzled; T(col-major) scratch aliases it band-wise
#define RED_OFF   131072   // 256 floats
#define LDS_BYTES 132096

__device__ __forceinline__ unsigned short f2bf(float f) {
  unsigned u = __float_as_uint(f);
  return (unsigned short)((u + 0x7FFFu + ((u >> 16) & 1u)) >> 16);  // RNE
}
__device__ __forceinline__ float bf2f(unsigned short h) {
  return __uint_as_float(((unsigned)h) << 16);
}
__device__ __forceinline__ f32x16 zero16() {
  f32x16 z;
#pragma unroll
  for (int i = 0; i < 16; ++i) z[i] = 0.0f;
  return z;
}
// XOR swizzle in a [R][128] bf16 buffer: 8-elem granule g -> g ^ (R&7).
__device__ __forceinline__ int swz8(int R, int k0) {  // k0 % 8 == 0
  return R * 128 + (((k0 >> 3) ^ (R & 7)) << 3);
}
__device__ __forceinline__ int swz4(int R, int c0) {  // c0 % 4 == 0
  return R * 128 + ((((c0 >> 3) ^ (R & 7)) << 3) | (c0 & 7));
}
__device__ __forceinline__ int swz1(int R, int c) {
  return R * 128 + ((((c >> 3) ^ (R & 7)) << 3) | (c & 7));
}

__global__ void __launch_bounds__(1024, 4)
ns_inverse_kernel(const float* __restrict__ Wglob, const int* __restrict__ nIt,
                  float* __restrict__ outglob) {
  extern __shared__ char lds[];
  float* stage = (float*)(lds + STAGE_OFF);
  unsigned short* xrm = (unsigned short*)(lds + XRM_OFF);
  unsigned short* xcm = (unsigned short*)(lds + XCM_OFF);   // also T scratch
  float* red = (float*)(lds + RED_OFF);

  const int b = blockIdx.x;
  const float* Wg = Wglob + (size_t)b * (NN * NN);
  float* outg = outglob + (size_t)b * (NN * NN);
  const int t = threadIdx.x;      // 0..1023
  const int lane = t & 63;
  const int wv = t >> 6;          // 0..15
  const int l31 = lane & 31;
  const int half = lane >> 5;
  const int s = wv & 3;           // strip: W rows (mm1 A) / X' rows (mm2 B, epi)
  const int v = wv >> 2;          // band: T cols (mm1 out) / X' cols (mm2 A, epi)
  const int niters = nIt[0];

  // ---- phase 0: stage W fp32 into LDS (the only global read) ----
  {
    const f32x4* src = (const f32x4*)Wg;
    f32x4* dst = (f32x4*)stage;
#pragma unroll
    for (int i = 0; i < 4; ++i) dst[t + 1024 * i] = src[t + 1024 * i];
  }
  __syncthreads();

  // ---- norms ----
  if (t < 128) {            // row sums (rotated start)
    float ssum = 0.f;
    for (int jj = 0; jj < NN; ++jj) { int j = (jj + t) & 127; ssum += fabsf(stage[t * NN + j]); }
    red[t] = ssum;
  } else if (t < 256) {     // col sums
    int c = t - 128;
    float ssum = 0.f;
    for (int i = 0; i < NN; ++i) ssum += fabsf(stage[i * NN + c]);
    red[128 + c] = ssum;
  }
  __syncthreads();
  float ninf = 0.f, n1 = 0.f;
  for (int i = 0; i < 128; ++i) {   // broadcast reads
    ninf = fmaxf(ninf, red[i]);
    n1   = fmaxf(n1,   red[128 + i]);
  }
  const float scale = 1.0f / (n1 * ninf);

  // ---- wfrag: W strip-s rows as hi-bf16 A-fragments (dup across v, fine) ----
  bf16x8 wfrag[8];
  {
    const int am = 32 * s + l31;
#pragma unroll
    for (int ks = 0; ks < 8; ++ks) {
      const float* p = stage + am * NN + ks * 16 + half * 8;
      f32x4 a = *(const f32x4*)p;
      f32x4 bq = *(const f32x4*)(p + 4);
      bf16x8 f;
      f[0] = (short)f2bf(a[0]);  f[1] = (short)f2bf(a[1]);
      f[2] = (short)f2bf(a[2]);  f[3] = (short)f2bf(a[3]);
      f[4] = (short)f2bf(bq[0]); f[5] = (short)f2bf(bq[1]);
      f[6] = (short)f2bf(bq[2]); f[7] = (short)f2bf(bq[3]);
      wfrag[ks] = f;
    }
  }

  // ---- X0 = W^T * scale ----
  // xcm row n = X0 col n = W row n : straight scaled copy from stage
#pragma unroll
  for (int i = 0; i < 4; ++i) {
    int e0 = (t + 1024 * i) * 4;
    int R = e0 >> 7, c0 = e0 & 127;
    f32x4 vv = *(const f32x4*)(stage + e0);
    us4 h4;
#pragma unroll
    for (int j = 0; j < 4; ++j) h4[j] = f2bf(vv[j] * scale);
    *(us4*)(xcm + swz4(R, c0)) = h4;
  }
  // xrm row r = X0 row r = W col r : LDS transpose from stage (2-way max)
  {
    const int r = t & 127;
    const int kc = (t >> 7) * 16;
#pragma unroll
    for (int j4 = 0; j4 < 4; ++j4) {
      int c0 = kc + j4 * 4;
      us4 h4;
#pragma unroll
      for (int i = 0; i < 4; ++i) h4[i] = f2bf(stage[(c0 + i) * NN + r] * scale);
      *(us4*)(xrm + swz4(r, c0)) = h4;
    }
  }
  __syncthreads();

  // ---------------- iterations: X' = 2X - X(WX) ----------------
  const int pX = 32 * s + l31;    // lane-owned X/X' row
  const int rv = 32 * v + l31;    // lane-owned xcm/scr row (= T col = X' col band)
  for (int it = 0; it < niters; ++it) {
    const bool last = (it == niters - 1);

    // ---- mm1: T tile rows [32s..), cols [32v..) ; B = xcm band v ----
    {
      f32x16 tt = zero16();
#pragma unroll
      for (int ks = 0; ks < 8; ++ks) {
        bf16x8 bv = *(const bf16x8*)(xcm + swz8(rv, ks * 16 + half * 8));
        tt = __builtin_amdgcn_mfma_f32_32x32x16_bf16(wfrag[ks], bv, tt, 0, 0, 0);
      }
      __syncthreads();   // B1: all mm1 xcm reads complete
      // write T tile into scr (=xcm) row rv (T col-major), cols = T rows strip s
#pragma unroll
      for (int q = 0; q < 4; ++q) {
        us4 h4;
#pragma unroll
        for (int i = 0; i < 4; ++i) h4[i] = f2bf(tt[4 * q + i]);
        *(us4*)(xcm + swz4(rv, 32 * s + 8 * q + 4 * half)) = h4;
      }
    }
    __syncthreads();     // B2: full T assembled in scr

    // ---- mm2: (X@T)^T tile rows (X' cols) [32v..), cols (X' rows) [32s..) ----
    f32x16 acc = zero16();
#pragma unroll
    for (int ks = 0; ks < 8; ++ks) {
      int k0 = ks * 16 + half * 8;
      bf16x8 av  = *(const bf16x8*)(xcm + swz8(rv, k0));   // scr row (T col-major)
      bf16x8 bvv = *(const bf16x8*)(xrm + swz8(pX, k0));   // old X row
      acc = __builtin_amdgcn_mfma_f32_32x32x16_bf16(av, bvv, acc, 0, 0, 0);
    }
    __syncthreads();     // B3: all scr + xrm reads complete

    // ---- epilogue: X'[pX][32v + m] = 2X - (X@T) ----
#pragma unroll
    for (int q = 0; q < 4; ++q) {
      int c0m = 32 * v + 8 * q + 4 * half;
      int offr = swz4(pX, c0m);
      us4 xh4 = *(const us4*)(xrm + offr);
      f32x4 vv;
#pragma unroll
      for (int i = 0; i < 4; ++i)
        vv[i] = 2.0f * bf2f(xh4[i]) - acc[4 * q + i];
      if (last) {
        *(f32x4*)(outg + pX * NN + c0m) = vv;
      } else {
        us4 h4;
#pragma unroll
        for (int i = 0; i < 4; ++i) {
          unsigned short hh = f2bf(vv[i]);
          h4[i] = hh;
          xcm[swz1(c0m + i, pX)] = hh;     // X' col-major (band v rows: self-owned)
        }
        *(us4*)(xrm + offr) = h4;
      }
    }
    __syncthreads();     // B4: X' committed before next mm1
  }
}

extern "C" void kernel_launch(void* const* d_in, const int* in_sizes, int n_in,
                              void* d_out, int out_size, void* d_ws, size_t ws_size,
                              hipStream_t stream) {
  const float* W = (const float*)d_in[0];
  const int* nIt = (const int*)d_in[1];
  float* out = (float*)d_out;
  const int nmat = in_sizes[0] / (NN * NN);   // 1024

  hipFuncSetAttribute((const void*)ns_inverse_kernel,
                      hipFuncAttributeMaxDynamicSharedMemorySize, LDS_BYTES);
  ns_inverse_kernel<<<nmat, 1024, LDS_BYTES, stream>>>(W, nIt, out);
}

// Round 6
// 203.605 us; speedup vs baseline: 1.2452x; 1.2452x over previous
//
#include <hip/hip_runtime.h>

// Newton-Schulz batched inverse, 1024 x (128x128) fp32.
// R6: zero register-resident state across the loop (W read per-MFMA from LDS
// wrm buffer) -> structurally spill-free at any arch/AGPR split.
// 1024 thr / 16 waves / 1 block/CU with 160KB LDS; 3 barriers/iter.
// hi-only bf16 X (2d0-d1-d2 cancellation), XOR-swizzled conflict-free layout.

#define NN 128

typedef __attribute__((ext_vector_type(8))) short bf16x8;
typedef __attribute__((ext_vector_type(16))) float f32x16;
typedef __attribute__((ext_vector_type(4))) float f32x4;
typedef __attribute__((ext_vector_type(4))) unsigned short us4;

// LDS layout (bytes):
#define WRM_OFF   0        // W row-major bf16 (unscaled)      32768
#define XRM_OFF   32768    // X row-major bf16                 32768
#define XCM_OFF   65536    // X col-major bf16                 32768
#define SCR_OFF   98304    // T col-major bf16                 32768
#define STAGE_OFF 98304    // fp32 W stage 65536 = [98304,163840); dead before scr use
#define RED_OFF   32768    // 256 floats in xrm region during phase 0 only
#define LDS_BYTES 163840

__device__ __forceinline__ unsigned short f2bf(float f) {
  unsigned u = __float_as_uint(f);
  return (unsigned short)((u + 0x7FFFu + ((u >> 16) & 1u)) >> 16);  // RNE
}
__device__ __forceinline__ float bf2f(unsigned short h) {
  return __uint_as_float(((unsigned)h) << 16);
}
__device__ __forceinline__ f32x16 zero16() {
  f32x16 z;
#pragma unroll
  for (int i = 0; i < 16; ++i) z[i] = 0.0f;
  return z;
}
// XOR swizzle in a [R][128] bf16 buffer: 8-elem granule g -> g ^ (R&7).
__device__ __forceinline__ int swz8(int R, int k0) {  // k0 % 8 == 0
  return R * 128 + (((k0 >> 3) ^ (R & 7)) << 3);
}
__device__ __forceinline__ int swz4(int R, int c0) {  // c0 % 4 == 0
  return R * 128 + ((((c0 >> 3) ^ (R & 7)) << 3) | (c0 & 7));
}
__device__ __forceinline__ int swz1(int R, int c) {
  return R * 128 + ((((c >> 3) ^ (R & 7)) << 3) | (c & 7));
}

__global__ void __launch_bounds__(1024)
ns_inverse_kernel(const float* __restrict__ Wglob, const int* __restrict__ nIt,
                  float* __restrict__ outglob) {
  extern __shared__ char lds[];
  unsigned short* wrm = (unsigned short*)(lds + WRM_OFF);
  unsigned short* xrm = (unsigned short*)(lds + XRM_OFF);
  unsigned short* xcm = (unsigned short*)(lds + XCM_OFF);
  unsigned short* scr = (unsigned short*)(lds + SCR_OFF);
  float* stage = (float*)(lds + STAGE_OFF);
  float* red   = (float*)(lds + RED_OFF);

  const int b = blockIdx.x;
  const float* Wg = Wglob + (size_t)b * (NN * NN);
  float* outg = outglob + (size_t)b * (NN * NN);
  const int t = threadIdx.x;      // 0..1023
  const int lane = t & 63;
  const int wv = t >> 6;          // 0..15
  const int l31 = lane & 31;
  const int half = lane >> 5;
  const int s = wv & 3;           // strip: W rows (mm1 A) / X' rows (mm2 B, epi)
  const int v = wv >> 2;          // band: T cols / X' cols (mm2 A, epi)
  const int niters = nIt[0];

  // ---- phase 0: stage W fp32 into LDS (only global read) ----
  {
    const f32x4* src = (const f32x4*)Wg;
    f32x4* dst = (f32x4*)stage;
#pragma unroll
    for (int i = 0; i < 4; ++i) dst[t + 1024 * i] = src[t + 1024 * i];
  }
  __syncthreads();

  // ---- norms (red lives in xrm region; xrm filled later) ----
  if (t < 128) {            // row sums (rotated start)
    float ssum = 0.f;
    for (int jj = 0; jj < NN; ++jj) { int j = (jj + t) & 127; ssum += fabsf(stage[t * NN + j]); }
    red[t] = ssum;
  } else if (t < 256) {     // col sums
    int c = t - 128;
    float ssum = 0.f;
    for (int i = 0; i < NN; ++i) ssum += fabsf(stage[i * NN + c]);
    red[128 + c] = ssum;
  }
  __syncthreads();
  float ninf = 0.f, n1 = 0.f;
  for (int i = 0; i < 128; ++i) {   // broadcast reads (same addr across lanes)
    ninf = fmaxf(ninf, red[i]);
    n1   = fmaxf(n1,   red[128 + i]);
  }
  const float scale = 1.0f / (n1 * ninf);
  __syncthreads();   // everyone has scale; red region may be overwritten now

  // ---- fills from stage ----
  // wrm row r = W row r (unscaled); xcm row r = X0 col r = W row r * scale
  {
    const int r = t >> 3;
    const int c0 = (t & 7) * 16;
#pragma unroll
    for (int h = 0; h < 4; ++h) {
      f32x4 a = *(const f32x4*)(stage + r * NN + c0 + 4 * h);
      us4 hw, hx;
#pragma unroll
      for (int i = 0; i < 4; ++i) {
        hw[i] = f2bf(a[i]);
        hx[i] = f2bf(a[i] * scale);
      }
      *(us4*)(wrm + swz4(r, c0 + 4 * h)) = hw;
      *(us4*)(xcm + swz4(r, c0 + 4 * h)) = hx;
    }
  }
  // xrm row r = X0 row r = W col r * scale (LDS transpose from stage)
  {
    const int r = t & 127;
    const int kc = (t >> 7) * 16;
#pragma unroll
    for (int j4 = 0; j4 < 4; ++j4) {
      int c0 = kc + 4 * j4;
      us4 h4;
#pragma unroll
      for (int i = 0; i < 4; ++i) h4[i] = f2bf(stage[(c0 + i) * NN + r] * scale);
      *(us4*)(xrm + swz4(r, c0)) = h4;
    }
  }
  __syncthreads();   // stage dead from here; scr region free

  // ---------------- iterations: X' = 2X - X(WX) ----------------
  const int pX = 32 * s + l31;    // lane-owned X/X' row
  const int rv = 32 * v + l31;    // lane-owned xcm/scr row (= T col = X' col band)
  for (int it = 0; it < niters; ++it) {
    const bool last = (it == niters - 1);

    // ---- mm1: T tile rows [32s..), cols [32v..): A=wrm, B=xcm (both LDS) ----
    {
      f32x16 tt = zero16();
#pragma unroll
      for (int ks = 0; ks < 8; ++ks) {
        int k0 = ks * 16 + half * 8;
        bf16x8 av = *(const bf16x8*)(wrm + swz8(pX, k0));
        bf16x8 bv = *(const bf16x8*)(xcm + swz8(rv, k0));
        tt = __builtin_amdgcn_mfma_f32_32x32x16_bf16(av, bv, tt, 0, 0, 0);
      }
      // write T tile into scr (T col-major): scr row rv, cols = T rows strip s
#pragma unroll
      for (int q = 0; q < 4; ++q) {
        us4 h4;
#pragma unroll
        for (int i = 0; i < 4; ++i) h4[i] = f2bf(tt[4 * q + i]);
        *(us4*)(scr + swz4(rv, 32 * s + 8 * q + 4 * half)) = h4;
      }
    }
    __syncthreads();   // B1: full T assembled

    // ---- mm2: (X@T)^T tile rows [32v..) (X' cols), cols [32s..) (X' rows) ----
    f32x16 acc = zero16();
#pragma unroll
    for (int ks = 0; ks < 8; ++ks) {
      int k0 = ks * 16 + half * 8;
      bf16x8 av = *(const bf16x8*)(scr + swz8(rv, k0));   // T col-major row
      bf16x8 bv = *(const bf16x8*)(xrm + swz8(pX, k0));   // old X row
      acc = __builtin_amdgcn_mfma_f32_32x32x16_bf16(av, bv, acc, 0, 0, 0);
    }
    __syncthreads();   // B2: all scr + xrm reads complete before overwrite

    // ---- epilogue: X'[pX][32v + m] = 2X - (X@T) ----
#pragma unroll
    for (int q = 0; q < 4; ++q) {
      int c0m = 32 * v + 8 * q + 4 * half;
      int offr = swz4(pX, c0m);
      us4 xh4 = *(const us4*)(xrm + offr);
      f32x4 vv;
#pragma unroll
      for (int i = 0; i < 4; ++i)
        vv[i] = 2.0f * bf2f(xh4[i]) - acc[4 * q + i];
      if (last) {
        *(f32x4*)(outg + pX * NN + c0m) = vv;
      } else {
        us4 h4;
#pragma unroll
        for (int i = 0; i < 4; ++i) {
          unsigned short hh = f2bf(vv[i]);
          h4[i] = hh;
          xcm[swz1(c0m + i, pX)] = hh;     // X' col-major
        }
        *(us4*)(xrm + offr) = h4;          // X' row-major
      }
    }
    __syncthreads();   // B3: X' committed before next mm1
  }
}

extern "C" void kernel_launch(void* const* d_in, const int* in_sizes, int n_in,
                              void* d_out, int out_size, void* d_ws, size_t ws_size,
                              hipStream_t stream) {
  const float* W = (const float*)d_in[0];
  const int* nIt = (const int*)d_in[1];
  float* out = (float*)d_out;
  const int nmat = in_sizes[0] / (NN * NN);   // 1024

  hipFuncSetAttribute((const void*)ns_inverse_kernel,
                      hipFuncAttributeMaxDynamicSharedMemorySize, LDS_BYTES);
  ns_inverse_kernel<<<nmat, 1024, LDS_BYTES, stream>>>(W, nIt, out);
}